// Round 1
// baseline (335.098 us; speedup 1.0000x reference)
//
#include <hip/hip_runtime.h>
#include <math.h>

#define NN 100000
#define EE 1600000
#define HH 128
#define RR 500
#define AA 16
#define LN_EPS 1e-5f

// ws layout (floats): deg[NN] | A[2*NN] (interleaved A0,A1) | S[HH] | T2[1]

__global__ void k_init(float* __restrict__ ws, int total, int n) {
    int i = blockIdx.x * blockDim.x + threadIdx.x;
    int stride = gridDim.x * blockDim.x;
    for (; i < total; i += stride)
        ws[i] = (i < n) ? 1.0f : 0.0f;   // deg starts at 1 (self-loop), rest 0
}

__global__ void k_deg(const int* __restrict__ dst, float* __restrict__ deg, int e) {
    int i = blockIdx.x * blockDim.x + threadIdx.x;
    int stride = gridDim.x * blockDim.x;
    for (; i < e; i += stride)
        atomicAdd(&deg[dst[i]], 1.0f);
}

__global__ void k_edge(const int* __restrict__ src, const int* __restrict__ dst,
                       const float* __restrict__ nf, const float* __restrict__ deg,
                       float* __restrict__ A, int e) {
    int i = blockIdx.x * blockDim.x + threadIdx.x;
    int stride = gridDim.x * blockDim.x;
    for (; i < e; i += stride) {
        int s = src[i], d = dst[i];
        float w = rsqrtf(deg[s]) * rsqrtf(deg[d]);
        float2 f = *reinterpret_cast<const float2*>(&nf[2 * s]);
        atomicAdd(&A[2 * d],     f.x * w);
        atomicAdd(&A[2 * d + 1], f.y * w);
    }
}

// 256 threads: channel = tid&127, node-slot = tid>>7 (2 nodes in flight per block)
__global__ void k_node(const float* __restrict__ nf, const float* __restrict__ deg,
                       const float* __restrict__ A,
                       const float* __restrict__ gcn_w, const float* __restrict__ gcn_b,
                       float* __restrict__ S, float* __restrict__ T2, int n) {
    const int ch   = threadIdx.x & (HH - 1);
    const int slot = threadIdx.x >> 7;      // 0 or 1
    const float w0 = gcn_w[ch];
    const float w1 = gcn_w[HH + ch];
    const float b  = gcn_b[ch];
    float accS = 0.f, accT2 = 0.f;
    for (int i = blockIdx.x * 2 + slot; i < n; i += gridDim.x * 2) {
        float invdeg = 1.0f / deg[i];        // dis*dis
        float b0 = A[2 * i]     + nf[2 * i]     * invdeg;
        float b1 = A[2 * i + 1] + nf[2 * i + 1] * invdeg;
        float x = fmaf(b0, w0, fmaf(b1, w1, b));
        float r = fmaxf(x, 0.f);
        accS  += r;
        accT2 += r * r;
    }
    __shared__ float shS[HH];
    if (slot == 1) shS[ch] = accS;
    __syncthreads();
    if (slot == 0) atomicAdd(&S[ch], accS + shS[ch]);
    // block-reduce T2 (sum of squares)
    float v = accT2;
    for (int o = 32; o; o >>= 1) v += __shfl_down(v, o, 64);
    __shared__ float shw[4];
    if ((threadIdx.x & 63) == 0) shw[threadIdx.x >> 6] = v;
    __syncthreads();
    if (threadIdx.x == 0) atomicAdd(T2, shw[0] + shw[1] + shw[2] + shw[3]);
}

// single block, 128 threads: LN-collapse + fc1 + fc2 + log_softmax
__global__ void k_final(const float* __restrict__ S, const float* __restrict__ T2ptr,
                        const float* __restrict__ esn,
                        const float* __restrict__ ln_w, const float* __restrict__ ln_b,
                        const float* __restrict__ fc1_w, const float* __restrict__ fc1_b,
                        const float* __restrict__ fc2_w, const float* __restrict__ fc2_b,
                        float* __restrict__ out) {
    const int t = threadIdx.x;  // 0..127
    __shared__ float sh_pooled[HH];
    __shared__ float sh_z[HH];
    __shared__ float sh_logits[AA];
    __shared__ float shred[2];

    float s = S[t];
    // T1 = sum over channels of S
    float v = s;
    for (int o = 32; o; o >>= 1) v += __shfl_down(v, o, 64);
    if ((t & 63) == 0) shred[t >> 6] = v;
    __syncthreads();
    const float T1 = shred[0] + shred[1];
    const float T2 = *T2ptr;
    const float cnt = (float)NN * (float)HH;
    const float mean = T1 / cnt;
    const float var  = T2 / cnt - mean * mean;
    const float denom = sqrtf(var) + LN_EPS;
    sh_pooled[t] = ln_w[t] * (s - (float)NN * mean) / denom + (float)NN * ln_b[t];
    __syncthreads();

    float acc = fc1_b[t];
    for (int k = 0; k < HH; ++k)
        acc = fmaf(sh_pooled[k], fc1_w[k * HH + t], acc);
    for (int k = 0; k < RR; ++k)
        acc = fmaf(esn[k], fc1_w[(HH + k) * HH + t], acc);
    sh_z[t] = fmaxf(acc, 0.f);
    __syncthreads();

    if (t < AA) {
        float l = fc2_b[t];
        for (int j = 0; j < HH; ++j)
            l = fmaf(sh_z[j], fc2_w[j * AA + t], l);
        sh_logits[t] = l;
    }
    __syncthreads();

    if (t == 0) {
        float m = sh_logits[0];
        for (int a = 1; a < AA; ++a) m = fmaxf(m, sh_logits[a]);
        float sum = 0.f;
        for (int a = 0; a < AA; ++a) sum += expf(sh_logits[a] - m);
        float lse = m + logf(sum);
        for (int a = 0; a < AA; ++a) out[a] = sh_logits[a] - lse;
    }
}

extern "C" void kernel_launch(void* const* d_in, const int* in_sizes, int n_in,
                              void* d_out, int out_size, void* d_ws, size_t ws_size,
                              hipStream_t stream) {
    const float* nf     = (const float*)d_in[0];
    const int*   ei     = (const int*)d_in[1];
    const float* esn    = (const float*)d_in[2];
    const float* gcn_w  = (const float*)d_in[3];
    const float* gcn_b  = (const float*)d_in[4];
    const float* ln_w   = (const float*)d_in[5];
    const float* ln_b   = (const float*)d_in[6];
    const float* fc1_w  = (const float*)d_in[7];
    const float* fc1_b  = (const float*)d_in[8];
    const float* fc2_w  = (const float*)d_in[9];
    const float* fc2_b  = (const float*)d_in[10];
    float* out = (float*)d_out;

    float* ws  = (float*)d_ws;
    float* deg = ws;                 // NN
    float* A   = ws + NN;            // 2*NN
    float* S   = ws + 3 * NN;        // HH
    float* T2  = ws + 3 * NN + HH;   // 1

    const int total_init = 3 * NN + HH + 1;
    hipLaunchKernelGGL(k_init, dim3(1024), dim3(256), 0, stream, ws, total_init, NN);
    hipLaunchKernelGGL(k_deg,  dim3(2048), dim3(256), 0, stream, ei + EE, deg, EE);
    hipLaunchKernelGGL(k_edge, dim3(2048), dim3(256), 0, stream, ei, ei + EE, nf, deg, A, EE);
    hipLaunchKernelGGL(k_node, dim3(256),  dim3(256), 0, stream, nf, deg, A, gcn_w, gcn_b, S, T2, NN);
    hipLaunchKernelGGL(k_final, dim3(1),   dim3(128), 0, stream,
                       S, T2, esn, ln_w, ln_b, fc1_w, fc1_b, fc2_w, fc2_b, out);
}

// Round 2
// 334.758 us; speedup vs baseline: 1.0010x; 1.0010x over previous
//
#include <hip/hip_runtime.h>
#include <math.h>

#define NN 100000
#define EE 1600000
#define HH 128
#define RR 500
#define AA 16
#define LN_EPS 1e-5f

// Physical XCD id (0..7 on MI355X). Verified working via learn_hip m09.
__device__ __forceinline__ int xcd_id() {
    int x;
    asm volatile("s_getreg_b32 %0, hwreg(HW_REG_XCC_ID)" : "=s"(x));
    return x & 7;
}

// Zero the accumulator region (uint4 bulk + scalar tail).
__global__ void k_init(unsigned int* __restrict__ p, int n) {
    int i = blockIdx.x * blockDim.x + threadIdx.x;
    int stride = gridDim.x * blockDim.x;
    int n4 = n >> 2;
    uint4* p4 = (uint4*)p;
    for (int j = i; j < n4; j += stride) p4[j] = make_uint4(0u, 0u, 0u, 0u);
    for (int j = (n4 << 2) + i; j < n; j += stride) p[j] = 0u;
}

// Degree histogram. NREP>1: XCD-local replica + workgroup-scope atomic (stays in local L2).
template<int NREP>
__global__ void k_deg(const int* __restrict__ dst, int* __restrict__ deg_rep, int e) {
    const int base = (NREP > 1) ? xcd_id() * NN : 0;
    int i = blockIdx.x * blockDim.x + threadIdx.x;
    if (i < e) {
        int d = dst[i];
        if (NREP > 1)
            __hip_atomic_fetch_add(&deg_rep[base + d], 1, __ATOMIC_RELAXED, __HIP_MEMORY_SCOPE_WORKGROUP);
        else
            atomicAdd(&deg_rep[d], 1);
    }
}

// Reduce degree replicas; emit degf[i] = deg (float) and g[i] = rsqrt(deg)*f[i] (float2).
template<int NREP>
__global__ void k_g(const int* __restrict__ deg_rep, const float* __restrict__ nf,
                    float* __restrict__ degf, float* __restrict__ g, int n) {
    int i = blockIdx.x * blockDim.x + threadIdx.x;
    if (i < n) {
        int dsum = 1;  // self-loop
        #pragma unroll
        for (int x = 0; x < NREP; ++x) dsum += deg_rep[(size_t)x * NN + i];
        float df = (float)dsum;
        degf[i] = df;
        float rs = rsqrtf(df);
        float2 f = *reinterpret_cast<const float2*>(&nf[2 * i]);
        float2 gv; gv.x = rs * f.x; gv.y = rs * f.y;
        *reinterpret_cast<float2*>(&g[2 * i]) = gv;
    }
}

// Edge scatter: B[d] += g[src]. NREP>1: XCD-local replica, L2-resident atomics.
template<int NREP>
__global__ void k_edge(const int* __restrict__ src, const int* __restrict__ dst,
                       const float* __restrict__ g, float* __restrict__ B_rep, int e) {
    const int base = (NREP > 1) ? xcd_id() * (2 * NN) : 0;
    int i = blockIdx.x * blockDim.x + threadIdx.x;
    if (i < e) {
        int s = src[i], d = dst[i];
        float2 gv = *reinterpret_cast<const float2*>(&g[2 * s]);
        if (NREP > 1) {
            __hip_atomic_fetch_add(&B_rep[base + 2 * d],     gv.x, __ATOMIC_RELAXED, __HIP_MEMORY_SCOPE_WORKGROUP);
            __hip_atomic_fetch_add(&B_rep[base + 2 * d + 1], gv.y, __ATOMIC_RELAXED, __HIP_MEMORY_SCOPE_WORKGROUP);
        } else {
            atomicAdd(&B_rep[2 * d],     gv.x);
            atomicAdd(&B_rep[2 * d + 1], gv.y);
        }
    }
}

// Node pass: x[i,ch] = relu((rs*B[i] + f[i]*invd) @ W + b); accumulate S[ch], T2.
// 256 threads: channel = tid&127, node-slot = tid>>7.
template<int NREP>
__global__ void k_node(const float* __restrict__ nf, const float* __restrict__ degf,
                       const float* __restrict__ B_rep,
                       const float* __restrict__ gcn_w, const float* __restrict__ gcn_b,
                       float* __restrict__ S, float* __restrict__ T2, int n) {
    const int ch   = threadIdx.x & (HH - 1);
    const int slot = threadIdx.x >> 7;
    const float w0 = gcn_w[ch];
    const float w1 = gcn_w[HH + ch];
    const float b  = gcn_b[ch];
    float accS = 0.f, accT2 = 0.f;
    for (int i = blockIdx.x * 2 + slot; i < n; i += gridDim.x * 2) {
        float df   = degf[i];
        float invd = 1.0f / df;
        float rs   = rsqrtf(df);
        float b0 = 0.f, b1 = 0.f;
        #pragma unroll
        for (int x = 0; x < NREP; ++x) {
            float2 bv = *reinterpret_cast<const float2*>(&B_rep[(size_t)x * 2 * NN + 2 * i]);
            b0 += bv.x; b1 += bv.y;
        }
        float2 f = *reinterpret_cast<const float2*>(&nf[2 * i]);
        b0 = rs * b0 + f.x * invd;
        b1 = rs * b1 + f.y * invd;
        float xv = fmaf(b0, w0, fmaf(b1, w1, b));
        float r  = fmaxf(xv, 0.f);
        accS  += r;
        accT2 += r * r;
    }
    __shared__ float shS[HH];
    if (slot == 1) shS[ch] = accS;
    __syncthreads();
    if (slot == 0) atomicAdd(&S[ch], accS + shS[ch]);
    float v = accT2;
    for (int o = 32; o; o >>= 1) v += __shfl_down(v, o, 64);
    __shared__ float shw[4];
    if ((threadIdx.x & 63) == 0) shw[threadIdx.x >> 6] = v;
    __syncthreads();
    if (threadIdx.x == 0) atomicAdd(T2, shw[0] + shw[1] + shw[2] + shw[3]);
}

// Single block, 128 threads: LN-collapse + fc1 + fc2 + log_softmax.
__global__ void k_final(const float* __restrict__ S, const float* __restrict__ T2ptr,
                        const float* __restrict__ esn,
                        const float* __restrict__ ln_w, const float* __restrict__ ln_b,
                        const float* __restrict__ fc1_w, const float* __restrict__ fc1_b,
                        const float* __restrict__ fc2_w, const float* __restrict__ fc2_b,
                        float* __restrict__ out) {
    const int t = threadIdx.x;
    __shared__ float sh_pooled[HH];
    __shared__ float sh_z[HH];
    __shared__ float sh_logits[AA];
    __shared__ float shred[2];

    float s = S[t];
    float v = s;
    for (int o = 32; o; o >>= 1) v += __shfl_down(v, o, 64);
    if ((t & 63) == 0) shred[t >> 6] = v;
    __syncthreads();
    const float T1 = shred[0] + shred[1];
    const float T2 = *T2ptr;
    const float cnt = (float)NN * (float)HH;
    const float mean = T1 / cnt;
    const float var  = T2 / cnt - mean * mean;
    const float denom = sqrtf(var) + LN_EPS;
    sh_pooled[t] = ln_w[t] * (s - (float)NN * mean) / denom + (float)NN * ln_b[t];
    __syncthreads();

    float acc = fc1_b[t];
    for (int k = 0; k < HH; ++k)
        acc = fmaf(sh_pooled[k], fc1_w[k * HH + t], acc);
    for (int k = 0; k < RR; ++k)
        acc = fmaf(esn[k], fc1_w[(HH + k) * HH + t], acc);
    sh_z[t] = fmaxf(acc, 0.f);
    __syncthreads();

    if (t < AA) {
        float l = fc2_b[t];
        for (int j = 0; j < HH; ++j)
            l = fmaf(sh_z[j], fc2_w[j * AA + t], l);
        sh_logits[t] = l;
    }
    __syncthreads();

    if (t == 0) {
        float m = sh_logits[0];
        for (int a = 1; a < AA; ++a) m = fmaxf(m, sh_logits[a]);
        float sum = 0.f;
        for (int a = 0; a < AA; ++a) sum += expf(sh_logits[a] - m);
        float lse = m + logf(sum);
        for (int a = 0; a < AA; ++a) out[a] = sh_logits[a] - lse;
    }
}

extern "C" void kernel_launch(void* const* d_in, const int* in_sizes, int n_in,
                              void* d_out, int out_size, void* d_ws, size_t ws_size,
                              hipStream_t stream) {
    const float* nf     = (const float*)d_in[0];
    const int*   ei     = (const int*)d_in[1];
    const float* esn    = (const float*)d_in[2];
    const float* gcn_w  = (const float*)d_in[3];
    const float* gcn_b  = (const float*)d_in[4];
    const float* ln_w   = (const float*)d_in[5];
    const float* ln_b   = (const float*)d_in[6];
    const float* fc1_w  = (const float*)d_in[7];
    const float* fc1_b  = (const float*)d_in[8];
    const float* fc2_w  = (const float*)d_in[9];
    const float* fc2_b  = (const float*)d_in[10];
    float* out = (float*)d_out;
    float* ws  = (float*)d_ws;

    const int eb = (EE + 255) / 256;
    const int nb = (NN + 255) / 256;

    // Replicated layout: deg_rep[8*NN] (int) | B_rep[16*NN] | S[128] | T2[1] | degf[NN] | g[2*NN]
    size_t need8 = ((size_t)24 * NN + HH + 1 + NN + 2 * NN) * 4;
    if (ws_size >= need8) {
        int*   deg_rep = (int*)ws;
        float* B_rep   = ws + (size_t)8 * NN;
        float* S       = ws + (size_t)24 * NN;
        float* T2      = ws + (size_t)24 * NN + HH;
        float* degf    = ws + (size_t)24 * NN + HH + 1;
        float* g       = ws + (size_t)25 * NN + HH + 1;
        const int nz = 24 * NN + HH + 1;
        hipLaunchKernelGGL(k_init,     dim3(2048), dim3(256), 0, stream, (unsigned int*)ws, nz);
        hipLaunchKernelGGL(k_deg<8>,   dim3(eb),   dim3(256), 0, stream, ei + EE, deg_rep, EE);
        hipLaunchKernelGGL(k_g<8>,     dim3(nb),   dim3(256), 0, stream, deg_rep, nf, degf, g, NN);
        hipLaunchKernelGGL(k_edge<8>,  dim3(eb),   dim3(256), 0, stream, ei, ei + EE, g, B_rep, EE);
        hipLaunchKernelGGL(k_node<8>,  dim3(512),  dim3(256), 0, stream, nf, degf, B_rep, gcn_w, gcn_b, S, T2, NN);
        hipLaunchKernelGGL(k_final,    dim3(1),    dim3(128), 0, stream,
                           S, T2, esn, ln_w, ln_b, fc1_w, fc1_b, fc2_w, fc2_b, out);
    } else {
        // Fallback: single-copy accumulators, agent-scope atomics (round-1 behavior).
        int*   deg_rep = (int*)ws;
        float* B_rep   = ws + (size_t)NN;
        float* S       = ws + (size_t)3 * NN;
        float* T2      = ws + (size_t)3 * NN + HH;
        float* degf    = ws + (size_t)3 * NN + HH + 1;
        float* g       = ws + (size_t)4 * NN + HH + 1;
        const int nz = 3 * NN + HH + 1;
        hipLaunchKernelGGL(k_init,     dim3(2048), dim3(256), 0, stream, (unsigned int*)ws, nz);
        hipLaunchKernelGGL(k_deg<1>,   dim3(eb),   dim3(256), 0, stream, ei + EE, deg_rep, EE);
        hipLaunchKernelGGL(k_g<1>,     dim3(nb),   dim3(256), 0, stream, deg_rep, nf, degf, g, NN);
        hipLaunchKernelGGL(k_edge<1>,  dim3(eb),   dim3(256), 0, stream, ei, ei + EE, g, B_rep, EE);
        hipLaunchKernelGGL(k_node<1>,  dim3(512),  dim3(256), 0, stream, nf, degf, B_rep, gcn_w, gcn_b, S, T2, NN);
        hipLaunchKernelGGL(k_final,    dim3(1),    dim3(128), 0, stream,
                           S, T2, esn, ln_w, ln_b, fc1_w, fc1_b, fc2_w, fc2_b, out);
    }
}

// Round 3
// 146.354 us; speedup vs baseline: 2.2896x; 2.2873x over previous
//
#include <hip/hip_runtime.h>
#include <math.h>

#define NN 100000
#define EE 1600000
#define HH 128
#define RR 500
#define AA 16
#define LN_EPS 1e-5f

// Bucketing: nodes -> 196 buckets of 512; payload packs (src<<9 | dst&511) in u32.
#define BSH 9
#define NPB 512                  // nodes per bucket
#define NB 196                   // ceil(NN/NPB)
#define MAXPB 9216               // mean 8163, sigma ~90 -> +11.7 sigma pad
#define EPW 8192                 // edges per scatter workgroup
#define NWG_SC ((EE + EPW - 1) / EPW)   // 196

__global__ void k_init(unsigned int* __restrict__ p, int n) {
    int i = blockIdx.x * blockDim.x + threadIdx.x;
    int stride = gridDim.x * blockDim.x;
    for (int j = i; j < n; j += stride) p[j] = 0u;
}

// ---------------- bucket path ----------------

// Bucket all edges by dst. Per-WG LDS histogram -> one global reserve atomic per
// (WG,bucket) -> payload writes to contiguous reserved slots.
__global__ __launch_bounds__(256) void k_scatter(const int* __restrict__ src,
                                                 const int* __restrict__ dst,
                                                 unsigned int* __restrict__ gctr,
                                                 unsigned int* __restrict__ payload) {
    __shared__ unsigned int hist[NB], hbase[NB], hist2[NB];
    const int t = threadIdx.x;
    if (t < NB) { hist[t] = 0u; hist2[t] = 0u; }
    __syncthreads();
    const int e0 = blockIdx.x * EPW;
    #pragma unroll 8
    for (int k = 0; k < EPW / 256; ++k) {
        int e = e0 + k * 256 + t;
        if (e < EE) atomicAdd(&hist[((unsigned)dst[e]) >> BSH], 1u);
    }
    __syncthreads();
    if (t < NB) hbase[t] = atomicAdd(&gctr[t], hist[t]);
    __syncthreads();
    #pragma unroll 8
    for (int k = 0; k < EPW / 256; ++k) {
        int e = e0 + k * 256 + t;
        if (e < EE) {
            unsigned int d = (unsigned)dst[e];
            unsigned int s = (unsigned)src[e];
            unsigned int b = d >> BSH;
            unsigned int r = atomicAdd(&hist2[b], 1u);
            unsigned int slot = hbase[b] + r;
            if (slot < MAXPB)
                payload[(size_t)b * MAXPB + slot] = (s << BSH) | (d & (NPB - 1));
        }
    }
}

// Per bucket: LDS degree histogram (no global atomics); write degf and g = rsqrt(deg)*f.
__global__ __launch_bounds__(256) void k_bdeg_g(const unsigned int* __restrict__ gctr,
                                                const unsigned int* __restrict__ payload,
                                                const float* __restrict__ nf,
                                                float* __restrict__ degf, float* __restrict__ g) {
    __shared__ unsigned int hist[NPB];
    const int b = blockIdx.x, t = threadIdx.x;
    for (int j = t; j < NPB; j += 256) hist[j] = 0u;
    __syncthreads();
    const unsigned int cnt = min(gctr[b], (unsigned int)MAXPB);
    const unsigned int* pl = payload + (size_t)b * MAXPB;
    for (unsigned int i = t; i < cnt; i += 256)
        atomicAdd(&hist[pl[i] & (NPB - 1)], 1u);
    __syncthreads();
    for (int j = t; j < NPB; j += 256) {
        int node = (b << BSH) + j;
        if (node < NN) {
            float df = 1.0f + (float)hist[j];
            degf[node] = df;
            float rs = rsqrtf(df);
            float2 f = *reinterpret_cast<const float2*>(&nf[2 * node]);
            float2 gv; gv.x = rs * f.x; gv.y = rs * f.y;
            *reinterpret_cast<float2*>(&g[2 * node]) = gv;
        }
    }
}

// Per bucket: gather g[src], LDS float accumulate, non-atomic store of owned B range.
__global__ __launch_bounds__(256) void k_bagg(const unsigned int* __restrict__ gctr,
                                              const unsigned int* __restrict__ payload,
                                              const float* __restrict__ g,
                                              float* __restrict__ B) {
    __shared__ float agg[NPB * 2];
    const int b = blockIdx.x, t = threadIdx.x;
    for (int j = t; j < NPB * 2; j += 256) agg[j] = 0.f;
    __syncthreads();
    const unsigned int cnt = min(gctr[b], (unsigned int)MAXPB);
    const unsigned int* pl = payload + (size_t)b * MAXPB;
    for (unsigned int i = t; i < cnt; i += 256) {
        unsigned int p = pl[i];
        unsigned int s = p >> BSH;
        unsigned int dl = p & (NPB - 1);
        float2 gv = *reinterpret_cast<const float2*>(&g[2 * s]);
        atomicAdd(&agg[2 * dl],     gv.x);
        atomicAdd(&agg[2 * dl + 1], gv.y);
    }
    __syncthreads();
    for (int j = t; j < NPB * 2; j += 256) {
        int idx = (b << BSH) * 2 + j;
        if (idx < 2 * NN) B[idx] = agg[j];
    }
}

// ---------------- fallback path (round-2 known-good) ----------------

__global__ void k_deg1(const int* __restrict__ dst, int* __restrict__ deg, int e) {
    int i = blockIdx.x * blockDim.x + threadIdx.x;
    if (i < e) atomicAdd(&deg[dst[i]], 1);
}

__global__ void k_g1(const int* __restrict__ deg, const float* __restrict__ nf,
                     float* __restrict__ degf, float* __restrict__ g, int n) {
    int i = blockIdx.x * blockDim.x + threadIdx.x;
    if (i < n) {
        float df = (float)(1 + deg[i]);
        degf[i] = df;
        float rs = rsqrtf(df);
        float2 f = *reinterpret_cast<const float2*>(&nf[2 * i]);
        float2 gv; gv.x = rs * f.x; gv.y = rs * f.y;
        *reinterpret_cast<float2*>(&g[2 * i]) = gv;
    }
}

__global__ void k_edge1(const int* __restrict__ src, const int* __restrict__ dst,
                        const float* __restrict__ g, float* __restrict__ B, int e) {
    int i = blockIdx.x * blockDim.x + threadIdx.x;
    if (i < e) {
        int s = src[i], d = dst[i];
        float2 gv = *reinterpret_cast<const float2*>(&g[2 * s]);
        atomicAdd(&B[2 * d],     gv.x);
        atomicAdd(&B[2 * d + 1], gv.y);
    }
}

// ---------------- shared tail ----------------

// x[i,ch] = relu((rs*B[i] + f[i]*invd) @ W + b); accumulate S[ch], T2.
__global__ void k_node(const float* __restrict__ nf, const float* __restrict__ degf,
                       const float* __restrict__ B,
                       const float* __restrict__ gcn_w, const float* __restrict__ gcn_b,
                       float* __restrict__ S, float* __restrict__ T2, int n) {
    const int ch   = threadIdx.x & (HH - 1);
    const int slot = threadIdx.x >> 7;
    const float w0 = gcn_w[ch];
    const float w1 = gcn_w[HH + ch];
    const float b  = gcn_b[ch];
    float accS = 0.f, accT2 = 0.f;
    for (int i = blockIdx.x * 2 + slot; i < n; i += gridDim.x * 2) {
        float df   = degf[i];
        float invd = 1.0f / df;
        float rs   = rsqrtf(df);
        float2 bv = *reinterpret_cast<const float2*>(&B[2 * i]);
        float2 f  = *reinterpret_cast<const float2*>(&nf[2 * i]);
        float b0 = rs * bv.x + f.x * invd;
        float b1 = rs * bv.y + f.y * invd;
        float xv = fmaf(b0, w0, fmaf(b1, w1, b));
        float r  = fmaxf(xv, 0.f);
        accS  += r;
        accT2 += r * r;
    }
    __shared__ float shS[HH];
    if (slot == 1) shS[ch] = accS;
    __syncthreads();
    if (slot == 0) atomicAdd(&S[ch], accS + shS[ch]);
    float v = accT2;
    for (int o = 32; o; o >>= 1) v += __shfl_down(v, o, 64);
    __shared__ float shw[4];
    if ((threadIdx.x & 63) == 0) shw[threadIdx.x >> 6] = v;
    __syncthreads();
    if (threadIdx.x == 0) atomicAdd(T2, shw[0] + shw[1] + shw[2] + shw[3]);
}

__global__ void k_final(const float* __restrict__ S, const float* __restrict__ T2ptr,
                        const float* __restrict__ esn,
                        const float* __restrict__ ln_w, const float* __restrict__ ln_b,
                        const float* __restrict__ fc1_w, const float* __restrict__ fc1_b,
                        const float* __restrict__ fc2_w, const float* __restrict__ fc2_b,
                        float* __restrict__ out) {
    const int t = threadIdx.x;
    __shared__ float sh_pooled[HH];
    __shared__ float sh_z[HH];
    __shared__ float sh_logits[AA];
    __shared__ float shred[2];

    float s = S[t];
    float v = s;
    for (int o = 32; o; o >>= 1) v += __shfl_down(v, o, 64);
    if ((t & 63) == 0) shred[t >> 6] = v;
    __syncthreads();
    const float T1 = shred[0] + shred[1];
    const float T2 = *T2ptr;
    const float cnt = (float)NN * (float)HH;
    const float mean = T1 / cnt;
    const float var  = T2 / cnt - mean * mean;
    const float denom = sqrtf(var) + LN_EPS;
    sh_pooled[t] = ln_w[t] * (s - (float)NN * mean) / denom + (float)NN * ln_b[t];
    __syncthreads();

    float acc = fc1_b[t];
    for (int k = 0; k < HH; ++k)
        acc = fmaf(sh_pooled[k], fc1_w[k * HH + t], acc);
    for (int k = 0; k < RR; ++k)
        acc = fmaf(esn[k], fc1_w[(HH + k) * HH + t], acc);
    sh_z[t] = fmaxf(acc, 0.f);
    __syncthreads();

    if (t < AA) {
        float l = fc2_b[t];
        for (int j = 0; j < HH; ++j)
            l = fmaf(sh_z[j], fc2_w[j * AA + t], l);
        sh_logits[t] = l;
    }
    __syncthreads();

    if (t == 0) {
        float m = sh_logits[0];
        for (int a = 1; a < AA; ++a) m = fmaxf(m, sh_logits[a]);
        float sum = 0.f;
        for (int a = 0; a < AA; ++a) sum += expf(sh_logits[a] - m);
        float lse = m + logf(sum);
        for (int a = 0; a < AA; ++a) out[a] = sh_logits[a] - lse;
    }
}

extern "C" void kernel_launch(void* const* d_in, const int* in_sizes, int n_in,
                              void* d_out, int out_size, void* d_ws, size_t ws_size,
                              hipStream_t stream) {
    const float* nf     = (const float*)d_in[0];
    const int*   ei     = (const int*)d_in[1];
    const float* esn    = (const float*)d_in[2];
    const float* gcn_w  = (const float*)d_in[3];
    const float* gcn_b  = (const float*)d_in[4];
    const float* ln_w   = (const float*)d_in[5];
    const float* ln_b   = (const float*)d_in[6];
    const float* fc1_w  = (const float*)d_in[7];
    const float* fc1_b  = (const float*)d_in[8];
    const float* fc2_w  = (const float*)d_in[9];
    const float* fc2_b  = (const float*)d_in[10];
    float* out = (float*)d_out;
    float* ws  = (float*)d_ws;

    const int nb = (NN + 255) / 256;

    // Bucket-path layout (word offsets):
    //   gctr:0(256) | S:256(128) | T2:384(1) | payload:512(NB*MAXPB) | degf | g | B
    const size_t PAYLOAD_W = (size_t)NB * MAXPB;           // 1,806,336
    const size_t OFF_PAYLOAD = 512;
    const size_t OFF_DEGF = OFF_PAYLOAD + PAYLOAD_W;
    const size_t OFF_G    = OFF_DEGF + NN;                 // even -> float2 ok
    const size_t OFF_B    = OFF_G + 2 * (size_t)NN;
    const size_t NEED_BKT = (OFF_B + 2 * (size_t)NN) * 4;

    if (ws_size >= NEED_BKT) {
        unsigned int* gctr    = (unsigned int*)ws;
        float*        S       = ws + 256;
        float*        T2      = ws + 384;
        unsigned int* payload = (unsigned int*)ws + OFF_PAYLOAD;
        float*        degf    = ws + OFF_DEGF;
        float*        g       = ws + OFF_G;
        float*        B       = ws + OFF_B;

        hipLaunchKernelGGL(k_init,    dim3(1),       dim3(256), 0, stream, (unsigned int*)ws, 512);
        hipLaunchKernelGGL(k_scatter, dim3(NWG_SC),  dim3(256), 0, stream, ei, ei + EE, gctr, payload);
        hipLaunchKernelGGL(k_bdeg_g,  dim3(NB),      dim3(256), 0, stream, gctr, payload, nf, degf, g);
        hipLaunchKernelGGL(k_bagg,    dim3(NB),      dim3(256), 0, stream, gctr, payload, g, B);
        hipLaunchKernelGGL(k_node,    dim3(512),     dim3(256), 0, stream, nf, degf, B, gcn_w, gcn_b, S, T2, NN);
        hipLaunchKernelGGL(k_final,   dim3(1),       dim3(128), 0, stream,
                           S, T2, esn, ln_w, ln_b, fc1_w, fc1_b, fc2_w, fc2_b, out);
    } else {
        // Fallback: known-good atomic path.
        // deg:0(NN) | B:NN(2NN) | S:3NN(128) | T2:3NN+128 | degf:3NN+130 | g:4NN+130
        int*   deg  = (int*)ws;
        float* B    = ws + NN;
        float* S    = ws + 3 * (size_t)NN;
        float* T2   = ws + 3 * (size_t)NN + 128;
        float* degf = ws + 3 * (size_t)NN + 130;
        float* g    = ws + 4 * (size_t)NN + 130;
        const int eb = (EE + 255) / 256;
        hipLaunchKernelGGL(k_init,  dim3(2048), dim3(256), 0, stream, (unsigned int*)ws, 3 * NN + 129);
        hipLaunchKernelGGL(k_deg1,  dim3(eb),   dim3(256), 0, stream, ei + EE, deg, EE);
        hipLaunchKernelGGL(k_g1,    dim3(nb),   dim3(256), 0, stream, deg, nf, degf, g, NN);
        hipLaunchKernelGGL(k_edge1, dim3(eb),   dim3(256), 0, stream, ei, ei + EE, g, B, EE);
        hipLaunchKernelGGL(k_node,  dim3(512),  dim3(256), 0, stream, nf, degf, B, gcn_w, gcn_b, S, T2, NN);
        hipLaunchKernelGGL(k_final, dim3(1),    dim3(128), 0, stream,
                           S, T2, esn, ln_w, ln_b, fc1_w, fc1_b, fc2_w, fc2_b, out);
    }
}

// Round 4
// 127.766 us; speedup vs baseline: 2.6227x; 1.1455x over previous
//
#include <hip/hip_runtime.h>
#include <math.h>

#define NN 100000
#define EE 1600000
#define HH 128
#define RR 500
#define AA 16
#define LN_EPS 1e-5f

// Bucketing: nodes -> 196 buckets of 512; payload packs (src<<9 | dst&511) in u32.
#define BSH 9
#define NPB 512
#define NB 196
#define MAXPB 9216               // mean 8163/bucket, +11 sigma pad
#define EPW 8192                 // edges per scatter workgroup
#define NWG_SC ((EE + EPW - 1) / EPW)   // 196

__global__ void k_init(unsigned int* __restrict__ p, int n) {
    int i = blockIdx.x * blockDim.x + threadIdx.x;
    int stride = gridDim.x * blockDim.x;
    for (int j = i; j < n; j += stride) p[j] = 0u;
}

// ---------------- bucket path ----------------

// Bucket all edges by dst with an LDS counting sort so global payload writes are
// contiguous coalesced runs. One global reserve atomic per (WG,bucket).
__global__ __launch_bounds__(256) void k_scatter(const int* __restrict__ src,
                                                 const int* __restrict__ dst,
                                                 unsigned int* __restrict__ gctr,
                                                 unsigned int* __restrict__ payload) {
    __shared__ unsigned int lpl[EPW];                       // 32 KB sorted payload
    __shared__ unsigned int hist[256], rank[256], hbase[256], lbase[256];
    const int t = threadIdx.x;
    hist[t] = 0u; rank[t] = 0u; hbase[t] = 0u;
    __syncthreads();
    const int e0 = blockIdx.x * EPW;
    const int ecnt = min(EPW, EE - e0);

    // pass A: bucket histogram
    for (int k = t; k < ecnt; k += 256)
        atomicAdd(&hist[((unsigned)dst[e0 + k]) >> BSH], 1u);
    __syncthreads();

    // reserve global space: one atomic per (WG,bucket)
    if (t < NB && hist[t] > 0u) hbase[t] = atomicAdd(&gctr[t], hist[t]);

    // exclusive prefix scan of hist -> lbase (Hillis-Steele over 256)
    lbase[t] = hist[t];
    __syncthreads();
    for (int off = 1; off < 256; off <<= 1) {
        unsigned int v = (t >= off) ? lbase[t - off] : 0u;
        __syncthreads();
        lbase[t] += v;
        __syncthreads();
    }
    unsigned int excl = lbase[t] - hist[t];
    __syncthreads();
    lbase[t] = excl;
    __syncthreads();

    // pass B: scatter into LDS, grouped by bucket
    for (int k = t; k < ecnt; k += 256) {
        unsigned int d = (unsigned)dst[e0 + k];
        unsigned int s = (unsigned)src[e0 + k];
        unsigned int b = d >> BSH;
        unsigned int r = atomicAdd(&rank[b], 1u);
        lpl[lbase[b] + r] = (s << BSH) | (d & (NPB - 1));
    }
    __syncthreads();

    // pass C: per-bucket coalesced writeout of contiguous runs
    for (int b = 0; b < NB; ++b) {
        unsigned int c  = rank[b];
        unsigned int gb = hbase[b];
        unsigned int lb = lbase[b];
        for (unsigned int k = t; k < c; k += 256) {
            unsigned int slot = gb + k;
            if (slot < MAXPB)
                payload[(size_t)b * MAXPB + slot] = lpl[lb + k];
        }
    }
}

// Per bucket: LDS degree histogram; write rsv = rsqrt(deg) and g = rsv*f.
__global__ __launch_bounds__(256) void k_bdeg_g(const unsigned int* __restrict__ gctr,
                                                const unsigned int* __restrict__ payload,
                                                const float* __restrict__ nf,
                                                float* __restrict__ rsv, float* __restrict__ g) {
    __shared__ unsigned int hist[NPB];
    const int b = blockIdx.x, t = threadIdx.x;
    for (int j = t; j < NPB; j += 256) hist[j] = 0u;
    __syncthreads();
    const unsigned int cnt = min(gctr[b], (unsigned int)MAXPB);
    const unsigned int* pl = payload + (size_t)b * MAXPB;
    for (unsigned int i = t; i < cnt; i += 256)
        atomicAdd(&hist[pl[i] & (NPB - 1)], 1u);
    __syncthreads();
    for (int j = t; j < NPB; j += 256) {
        int node = (b << BSH) + j;
        if (node < NN) {
            float df = 1.0f + (float)hist[j];
            float rs = rsqrtf(df);
            rsv[node] = rs;
            float2 f = *reinterpret_cast<const float2*>(&nf[2 * node]);
            float2 gv; gv.x = rs * f.x; gv.y = rs * f.y;
            *reinterpret_cast<float2*>(&g[2 * node]) = gv;
        }
    }
}

// Per bucket: aggregate g[src] in LDS, fold self-loop (b = rs*(agg+g)), then the
// GCN channel pass + relu + S/T2 partial reduction — all from LDS. No B buffer.
__global__ __launch_bounds__(256) void k_bagg_node(const unsigned int* __restrict__ gctr,
        const unsigned int* __restrict__ payload,
        const float* __restrict__ g, const float* __restrict__ rsv,
        const float* __restrict__ gcn_w, const float* __restrict__ gcn_b,
        float* __restrict__ S, float* __restrict__ T2) {
    __shared__ float agg[NPB * 2];
    const int b = blockIdx.x, t = threadIdx.x;
    for (int j = t; j < NPB * 2; j += 256) agg[j] = 0.f;
    __syncthreads();
    const unsigned int cnt = min(gctr[b], (unsigned int)MAXPB);
    const unsigned int* pl = payload + (size_t)b * MAXPB;
    #pragma unroll 4
    for (unsigned int i = t; i < cnt; i += 256) {
        unsigned int p = pl[i];
        unsigned int s = p >> BSH;
        unsigned int dl = p & (NPB - 1);
        float2 gv = *reinterpret_cast<const float2*>(&g[2 * s]);
        atomicAdd(&agg[2 * dl],     gv.x);
        atomicAdd(&agg[2 * dl + 1], gv.y);
    }
    __syncthreads();

    const int nvalid = min(NPB, NN - (b << BSH));
    for (int j = t; j < nvalid; j += 256) {
        int node = (b << BSH) + j;
        float rs = rsv[node];
        float2 gv = *reinterpret_cast<const float2*>(&g[2 * node]);
        agg[2 * j]     = rs * (agg[2 * j]     + gv.x);
        agg[2 * j + 1] = rs * (agg[2 * j + 1] + gv.y);
    }
    __syncthreads();

    // channel pass: ch = t&127, two nodes in flight (slot = t>>7)
    const int ch = t & (HH - 1), slot = t >> 7;
    const float w0 = gcn_w[ch], w1 = gcn_w[HH + ch], bb = gcn_b[ch];
    float accS = 0.f, accT2 = 0.f;
    for (int j = slot; j < nvalid; j += 2) {
        float b0 = agg[2 * j], b1 = agg[2 * j + 1];
        float x = fmaf(b0, w0, fmaf(b1, w1, bb));
        float r = fmaxf(x, 0.f);
        accS  += r;
        accT2 += r * r;
    }
    __shared__ float shS[HH];
    if (slot == 1) shS[ch] = accS;
    __syncthreads();
    if (slot == 0) atomicAdd(&S[ch], accS + shS[ch]);
    float v = accT2;
    for (int o = 32; o; o >>= 1) v += __shfl_down(v, o, 64);
    __shared__ float shw[4];
    if ((t & 63) == 0) shw[t >> 6] = v;
    __syncthreads();
    if (t == 0) atomicAdd(T2, shw[0] + shw[1] + shw[2] + shw[3]);
}

// ---------------- fallback path (round-2 known-good) ----------------

__global__ void k_deg1(const int* __restrict__ dst, int* __restrict__ deg, int e) {
    int i = blockIdx.x * blockDim.x + threadIdx.x;
    if (i < e) atomicAdd(&deg[dst[i]], 1);
}

__global__ void k_g1(const int* __restrict__ deg, const float* __restrict__ nf,
                     float* __restrict__ degf, float* __restrict__ g, int n) {
    int i = blockIdx.x * blockDim.x + threadIdx.x;
    if (i < n) {
        float df = (float)(1 + deg[i]);
        degf[i] = df;
        float rs = rsqrtf(df);
        float2 f = *reinterpret_cast<const float2*>(&nf[2 * i]);
        float2 gv; gv.x = rs * f.x; gv.y = rs * f.y;
        *reinterpret_cast<float2*>(&g[2 * i]) = gv;
    }
}

__global__ void k_edge1(const int* __restrict__ src, const int* __restrict__ dst,
                        const float* __restrict__ g, float* __restrict__ B, int e) {
    int i = blockIdx.x * blockDim.x + threadIdx.x;
    if (i < e) {
        int s = src[i], d = dst[i];
        float2 gv = *reinterpret_cast<const float2*>(&g[2 * s]);
        atomicAdd(&B[2 * d],     gv.x);
        atomicAdd(&B[2 * d + 1], gv.y);
    }
}

__global__ void k_node(const float* __restrict__ nf, const float* __restrict__ degf,
                       const float* __restrict__ B,
                       const float* __restrict__ gcn_w, const float* __restrict__ gcn_b,
                       float* __restrict__ S, float* __restrict__ T2, int n) {
    const int ch   = threadIdx.x & (HH - 1);
    const int slot = threadIdx.x >> 7;
    const float w0 = gcn_w[ch];
    const float w1 = gcn_w[HH + ch];
    const float b  = gcn_b[ch];
    float accS = 0.f, accT2 = 0.f;
    for (int i = blockIdx.x * 2 + slot; i < n; i += gridDim.x * 2) {
        float df   = degf[i];
        float invd = 1.0f / df;
        float rs   = rsqrtf(df);
        float2 bv = *reinterpret_cast<const float2*>(&B[2 * i]);
        float2 f  = *reinterpret_cast<const float2*>(&nf[2 * i]);
        float b0 = rs * bv.x + f.x * invd;
        float b1 = rs * bv.y + f.y * invd;
        float xv = fmaf(b0, w0, fmaf(b1, w1, b));
        float r  = fmaxf(xv, 0.f);
        accS  += r;
        accT2 += r * r;
    }
    __shared__ float shS[HH];
    if (slot == 1) shS[ch] = accS;
    __syncthreads();
    if (slot == 0) atomicAdd(&S[ch], accS + shS[ch]);
    float v = accT2;
    for (int o = 32; o; o >>= 1) v += __shfl_down(v, o, 64);
    __shared__ float shw[4];
    if ((threadIdx.x & 63) == 0) shw[threadIdx.x >> 6] = v;
    __syncthreads();
    if (threadIdx.x == 0) atomicAdd(T2, shw[0] + shw[1] + shw[2] + shw[3]);
}

// ---------------- shared tail ----------------

__global__ void k_final(const float* __restrict__ S, const float* __restrict__ T2ptr,
                        const float* __restrict__ esn,
                        const float* __restrict__ ln_w, const float* __restrict__ ln_b,
                        const float* __restrict__ fc1_w, const float* __restrict__ fc1_b,
                        const float* __restrict__ fc2_w, const float* __restrict__ fc2_b,
                        float* __restrict__ out) {
    const int t = threadIdx.x;
    __shared__ float sh_pooled[HH];
    __shared__ float sh_z[HH];
    __shared__ float sh_logits[AA];
    __shared__ float shred[2];

    float s = S[t];
    float v = s;
    for (int o = 32; o; o >>= 1) v += __shfl_down(v, o, 64);
    if ((t & 63) == 0) shred[t >> 6] = v;
    __syncthreads();
    const float T1 = shred[0] + shred[1];
    const float T2 = *T2ptr;
    const float cnt = (float)NN * (float)HH;
    const float mean = T1 / cnt;
    const float var  = T2 / cnt - mean * mean;
    const float denom = sqrtf(var) + LN_EPS;
    sh_pooled[t] = ln_w[t] * (s - (float)NN * mean) / denom + (float)NN * ln_b[t];
    __syncthreads();

    float acc = fc1_b[t];
    for (int k = 0; k < HH; ++k)
        acc = fmaf(sh_pooled[k], fc1_w[k * HH + t], acc);
    for (int k = 0; k < RR; ++k)
        acc = fmaf(esn[k], fc1_w[(HH + k) * HH + t], acc);
    sh_z[t] = fmaxf(acc, 0.f);
    __syncthreads();

    if (t < AA) {
        float l = fc2_b[t];
        for (int j = 0; j < HH; ++j)
            l = fmaf(sh_z[j], fc2_w[j * AA + t], l);
        sh_logits[t] = l;
    }
    __syncthreads();

    if (t == 0) {
        float m = sh_logits[0];
        for (int a = 1; a < AA; ++a) m = fmaxf(m, sh_logits[a]);
        float sum = 0.f;
        for (int a = 0; a < AA; ++a) sum += expf(sh_logits[a] - m);
        float lse = m + logf(sum);
        for (int a = 0; a < AA; ++a) out[a] = sh_logits[a] - lse;
    }
}

extern "C" void kernel_launch(void* const* d_in, const int* in_sizes, int n_in,
                              void* d_out, int out_size, void* d_ws, size_t ws_size,
                              hipStream_t stream) {
    const float* nf     = (const float*)d_in[0];
    const int*   ei     = (const int*)d_in[1];
    const float* esn    = (const float*)d_in[2];
    const float* gcn_w  = (const float*)d_in[3];
    const float* gcn_b  = (const float*)d_in[4];
    const float* ln_w   = (const float*)d_in[5];
    const float* ln_b   = (const float*)d_in[6];
    const float* fc1_w  = (const float*)d_in[7];
    const float* fc1_b  = (const float*)d_in[8];
    const float* fc2_w  = (const float*)d_in[9];
    const float* fc2_b  = (const float*)d_in[10];
    float* out = (float*)d_out;
    float* ws  = (float*)d_ws;

    // Bucket-path layout (word offsets):
    //   gctr:0(256) | S:256(128) | T2:384 | payload:512(NB*MAXPB) | rsv(NN) | g(2NN)
    const size_t PAYLOAD_W   = (size_t)NB * MAXPB;     // 1,806,336
    const size_t OFF_PAYLOAD = 512;
    const size_t OFF_RSV     = OFF_PAYLOAD + PAYLOAD_W;
    const size_t OFF_G       = OFF_RSV + NN;           // even -> float2 ok
    const size_t NEED_BKT    = (OFF_G + 2 * (size_t)NN) * 4;

    if (ws_size >= NEED_BKT) {
        unsigned int* gctr    = (unsigned int*)ws;
        float*        S       = ws + 256;
        float*        T2      = ws + 384;
        unsigned int* payload = (unsigned int*)ws + OFF_PAYLOAD;
        float*        rsv     = ws + OFF_RSV;
        float*        g       = ws + OFF_G;

        hipLaunchKernelGGL(k_init,      dim3(1),      dim3(256), 0, stream, (unsigned int*)ws, 512);
        hipLaunchKernelGGL(k_scatter,   dim3(NWG_SC), dim3(256), 0, stream, ei, ei + EE, gctr, payload);
        hipLaunchKernelGGL(k_bdeg_g,    dim3(NB),     dim3(256), 0, stream, gctr, payload, nf, rsv, g);
        hipLaunchKernelGGL(k_bagg_node, dim3(NB),     dim3(256), 0, stream, gctr, payload, g, rsv, gcn_w, gcn_b, S, T2);
        hipLaunchKernelGGL(k_final,     dim3(1),      dim3(128), 0, stream,
                           S, T2, esn, ln_w, ln_b, fc1_w, fc1_b, fc2_w, fc2_b, out);
    } else {
        // Fallback: known-good atomic path.
        // deg:0(NN) | B:NN(2NN) | S:3NN(128) | T2:3NN+128 | degf:3NN+130 | g:4NN+130
        int*   deg  = (int*)ws;
        float* B    = ws + NN;
        float* S    = ws + 3 * (size_t)NN;
        float* T2   = ws + 3 * (size_t)NN + 128;
        float* degf = ws + 3 * (size_t)NN + 130;
        float* g    = ws + 4 * (size_t)NN + 130;
        const int eb = (EE + 255) / 256;
        const int nb = (NN + 255) / 256;
        hipLaunchKernelGGL(k_init,  dim3(2048), dim3(256), 0, stream, (unsigned int*)ws, 3 * NN + 129);
        hipLaunchKernelGGL(k_deg1,  dim3(eb),   dim3(256), 0, stream, ei + EE, deg, EE);
        hipLaunchKernelGGL(k_g1,    dim3(nb),   dim3(256), 0, stream, deg, nf, degf, g, NN);
        hipLaunchKernelGGL(k_edge1, dim3(eb),   dim3(256), 0, stream, ei, ei + EE, g, B, EE);
        hipLaunchKernelGGL(k_node,  dim3(512),  dim3(256), 0, stream, nf, degf, B, gcn_w, gcn_b, S, T2, NN);
        hipLaunchKernelGGL(k_final, dim3(1),    dim3(128), 0, stream,
                           S, T2, esn, ln_w, ln_b, fc1_w, fc1_b, fc2_w, fc2_b, out);
    }
}

// Round 5
// 79.582 us; speedup vs baseline: 4.2107x; 1.6055x over previous
//
#include <hip/hip_runtime.h>
#include <math.h>

#define NN 100000
#define EE 1600000
#define HH 128
#define RR 500
#define AA 16
#define LN_EPS 1e-5f

// Bucketing: nodes -> 196 buckets of 512; payload packs (src<<9 | dst&511) in u32.
#define BSH 9
#define NPB 512
#define NB 196
#define MAXPB 9216               // mean 8163/bucket, +11 sigma pad
#define EPW 8192                 // edges per scatter workgroup
#define SCT 512                  // scatter threads
#define NWG_SC ((EE + EPW - 1) / EPW)   // 196

__global__ void k_init(unsigned int* __restrict__ p, int n) {
    int i = blockIdx.x * blockDim.x + threadIdx.x;
    int stride = gridDim.x * blockDim.x;
    for (int j = i; j < n; j += stride) p[j] = 0u;
}

// ---------------- bucket path ----------------

// Bucket edges by dst: LDS bucket histogram -> one reserve atomic per (WG,bucket)
// -> per-edge LDS rank atomic + direct global payload write (L2 write-combined).
__global__ __launch_bounds__(SCT) void k_scatter(const int* __restrict__ src,
                                                 const int* __restrict__ dst,
                                                 unsigned int* __restrict__ gctr,
                                                 unsigned int* __restrict__ payload) {
    __shared__ unsigned int hist[256], rank[256], hbase[256];
    const int t = threadIdx.x;
    if (t < 256) { hist[t] = 0u; rank[t] = 0u; hbase[t] = 0u; }
    __syncthreads();
    const int e0 = blockIdx.x * EPW;
    const int ecnt = min(EPW, EE - e0);           // e0 mult of 8192, EE mult of 4 -> ecnt mult of 4
    const int nv = ecnt >> 2;
    const int4* d4 = reinterpret_cast<const int4*>(dst + e0);
    const int4* s4 = reinterpret_cast<const int4*>(src + e0);

    // pass A: bucket histogram (vectorized)
    for (int k = t; k < nv; k += SCT) {
        int4 d = d4[k];
        atomicAdd(&hist[((unsigned)d.x) >> BSH], 1u);
        atomicAdd(&hist[((unsigned)d.y) >> BSH], 1u);
        atomicAdd(&hist[((unsigned)d.z) >> BSH], 1u);
        atomicAdd(&hist[((unsigned)d.w) >> BSH], 1u);
    }
    __syncthreads();

    // reserve global space: one atomic per (WG,bucket)
    if (t < NB && hist[t] > 0u) hbase[t] = atomicAdd(&gctr[t], hist[t]);
    __syncthreads();

    // pass B: rank within (WG,bucket), direct global write
    for (int k = t; k < nv; k += SCT) {
        int4 d = d4[k];
        int4 s = s4[k];
        #define EMIT(SS, DD) { \
            unsigned int dd = (unsigned)(DD), ss = (unsigned)(SS); \
            unsigned int b = dd >> BSH; \
            unsigned int r = atomicAdd(&rank[b], 1u); \
            unsigned int slot = hbase[b] + r; \
            if (slot < MAXPB) payload[(size_t)b * MAXPB + slot] = (ss << BSH) | (dd & (NPB - 1)); }
        EMIT(s.x, d.x) EMIT(s.y, d.y) EMIT(s.z, d.z) EMIT(s.w, d.w)
        #undef EMIT
    }
}

// Per bucket, 1024 threads: LDS degree histogram; write rsv = rsqrt(deg), g = rsv*f.
__global__ __launch_bounds__(1024) void k_bdeg_g(const unsigned int* __restrict__ gctr,
                                                 const unsigned int* __restrict__ payload,
                                                 const float* __restrict__ nf,
                                                 float* __restrict__ rsv, float* __restrict__ g) {
    __shared__ unsigned int hist[NPB];
    const int b = blockIdx.x, t = threadIdx.x;
    if (t < NPB) hist[t] = 0u;
    __syncthreads();
    const unsigned int cnt = min(gctr[b], (unsigned int)MAXPB);
    const unsigned int* pl = payload + (size_t)b * MAXPB;
    const uint4* pl4 = reinterpret_cast<const uint4*>(pl);
    const unsigned int nv = cnt >> 2;
    for (unsigned int k = t; k < nv; k += 1024) {
        uint4 p = pl4[k];
        atomicAdd(&hist[p.x & (NPB - 1)], 1u);
        atomicAdd(&hist[p.y & (NPB - 1)], 1u);
        atomicAdd(&hist[p.z & (NPB - 1)], 1u);
        atomicAdd(&hist[p.w & (NPB - 1)], 1u);
    }
    for (unsigned int k = (nv << 2) + t; k < cnt; k += 1024)
        atomicAdd(&hist[pl[k] & (NPB - 1)], 1u);
    __syncthreads();
    if (t < NPB) {
        int node = (b << BSH) + t;
        if (node < NN) {
            float df = 1.0f + (float)hist[t];
            float rs = rsqrtf(df);
            rsv[node] = rs;
            float2 f = *reinterpret_cast<const float2*>(&nf[2 * node]);
            float2 gv; gv.x = rs * f.x; gv.y = rs * f.y;
            *reinterpret_cast<float2*>(&g[2 * node]) = gv;
        }
    }
}

// Per bucket, 1024 threads: aggregate g[src] into x/y LDS planes, fold self-loop
// (b = rs*(agg+g)), then GCN channel pass + relu + S/T2 partial reduction.
__global__ __launch_bounds__(1024) void k_bagg_node(const unsigned int* __restrict__ gctr,
        const unsigned int* __restrict__ payload,
        const float* __restrict__ g, const float* __restrict__ rsv,
        const float* __restrict__ gcn_w, const float* __restrict__ gcn_b,
        float* __restrict__ S, float* __restrict__ T2) {
    __shared__ float agg[NPB * 2];      // plane 0: x, plane 1: y (full 32-bank spread)
    __shared__ float shSf[HH];
    __shared__ float shw[16];
    const int b = blockIdx.x, t = threadIdx.x;
    agg[t] = 0.f;                        // 1024 == NPB*2
    if (t < HH) shSf[t] = 0.f;
    __syncthreads();
    const unsigned int cnt = min(gctr[b], (unsigned int)MAXPB);
    const unsigned int* pl = payload + (size_t)b * MAXPB;
    const uint4* pl4 = reinterpret_cast<const uint4*>(pl);
    const unsigned int nv = cnt >> 2;
    for (unsigned int k = t; k < nv; k += 1024) {
        uint4 p = pl4[k];
        #define ACC(P) { \
            unsigned int s = (P) >> BSH, dl = (P) & (NPB - 1); \
            float2 gv = *reinterpret_cast<const float2*>(&g[2 * s]); \
            atomicAdd(&agg[dl],       gv.x); \
            atomicAdd(&agg[NPB + dl], gv.y); }
        ACC(p.x) ACC(p.y) ACC(p.z) ACC(p.w)
        #undef ACC
    }
    for (unsigned int k = (nv << 2) + t; k < cnt; k += 1024) {
        unsigned int p = pl[k];
        unsigned int s = p >> BSH, dl = p & (NPB - 1);
        float2 gv = *reinterpret_cast<const float2*>(&g[2 * s]);
        atomicAdd(&agg[dl],       gv.x);
        atomicAdd(&agg[NPB + dl], gv.y);
    }
    __syncthreads();

    const int nvalid = min(NPB, NN - (b << BSH));
    if (t < nvalid) {
        int node = (b << BSH) + t;
        float rs = rsv[node];
        float2 gv = *reinterpret_cast<const float2*>(&g[2 * node]);
        agg[t]       = rs * (agg[t]       + gv.x);
        agg[NPB + t] = rs * (agg[NPB + t] + gv.y);
    }
    __syncthreads();

    // channel pass: ch = t&127, 8 node slots (slot = t>>7)
    const int ch = t & (HH - 1), slot = t >> 7;
    const float w0 = gcn_w[ch], w1 = gcn_w[HH + ch], bb = gcn_b[ch];
    float accS = 0.f, accT2 = 0.f;
    for (int j = slot; j < nvalid; j += 8) {
        float x = fmaf(agg[j], w0, fmaf(agg[NPB + j], w1, bb));
        float r = fmaxf(x, 0.f);
        accS  += r;
        accT2 += r * r;
    }
    atomicAdd(&shSf[ch], accS);          // LDS float atomic, 8-way same-address
    float v = accT2;
    for (int o = 32; o; o >>= 1) v += __shfl_down(v, o, 64);
    if ((t & 63) == 0) shw[t >> 6] = v;
    __syncthreads();
    if (t < HH) atomicAdd(&S[t], shSf[t]);
    if (t == 0) {
        float s2 = 0.f;
        #pragma unroll
        for (int w = 0; w < 16; ++w) s2 += shw[w];
        atomicAdd(T2, s2);
    }
}

// ---------------- fallback path (round-2 known-good) ----------------

__global__ void k_deg1(const int* __restrict__ dst, int* __restrict__ deg, int e) {
    int i = blockIdx.x * blockDim.x + threadIdx.x;
    if (i < e) atomicAdd(&deg[dst[i]], 1);
}

__global__ void k_g1(const int* __restrict__ deg, const float* __restrict__ nf,
                     float* __restrict__ degf, float* __restrict__ g, int n) {
    int i = blockIdx.x * blockDim.x + threadIdx.x;
    if (i < n) {
        float df = (float)(1 + deg[i]);
        degf[i] = df;
        float rs = rsqrtf(df);
        float2 f = *reinterpret_cast<const float2*>(&nf[2 * i]);
        float2 gv; gv.x = rs * f.x; gv.y = rs * f.y;
        *reinterpret_cast<float2*>(&g[2 * i]) = gv;
    }
}

__global__ void k_edge1(const int* __restrict__ src, const int* __restrict__ dst,
                        const float* __restrict__ g, float* __restrict__ B, int e) {
    int i = blockIdx.x * blockDim.x + threadIdx.x;
    if (i < e) {
        int s = src[i], d = dst[i];
        float2 gv = *reinterpret_cast<const float2*>(&g[2 * s]);
        atomicAdd(&B[2 * d],     gv.x);
        atomicAdd(&B[2 * d + 1], gv.y);
    }
}

__global__ void k_node(const float* __restrict__ nf, const float* __restrict__ degf,
                       const float* __restrict__ B,
                       const float* __restrict__ gcn_w, const float* __restrict__ gcn_b,
                       float* __restrict__ S, float* __restrict__ T2, int n) {
    const int ch   = threadIdx.x & (HH - 1);
    const int slot = threadIdx.x >> 7;
    const float w0 = gcn_w[ch];
    const float w1 = gcn_w[HH + ch];
    const float b  = gcn_b[ch];
    float accS = 0.f, accT2 = 0.f;
    for (int i = blockIdx.x * 2 + slot; i < n; i += gridDim.x * 2) {
        float df   = degf[i];
        float invd = 1.0f / df;
        float rs   = rsqrtf(df);
        float2 bv = *reinterpret_cast<const float2*>(&B[2 * i]);
        float2 f  = *reinterpret_cast<const float2*>(&nf[2 * i]);
        float b0 = rs * bv.x + f.x * invd;
        float b1 = rs * bv.y + f.y * invd;
        float xv = fmaf(b0, w0, fmaf(b1, w1, b));
        float r  = fmaxf(xv, 0.f);
        accS  += r;
        accT2 += r * r;
    }
    __shared__ float shS[HH];
    if (slot == 1) shS[ch] = accS;
    __syncthreads();
    if (slot == 0) atomicAdd(&S[ch], accS + shS[ch]);
    float v = accT2;
    for (int o = 32; o; o >>= 1) v += __shfl_down(v, o, 64);
    __shared__ float shw[4];
    if ((threadIdx.x & 63) == 0) shw[threadIdx.x >> 6] = v;
    __syncthreads();
    if (threadIdx.x == 0) atomicAdd(T2, shw[0] + shw[1] + shw[2] + shw[3]);
}

// ---------------- shared tail ----------------

__global__ void k_final(const float* __restrict__ S, const float* __restrict__ T2ptr,
                        const float* __restrict__ esn,
                        const float* __restrict__ ln_w, const float* __restrict__ ln_b,
                        const float* __restrict__ fc1_w, const float* __restrict__ fc1_b,
                        const float* __restrict__ fc2_w, const float* __restrict__ fc2_b,
                        float* __restrict__ out) {
    const int t = threadIdx.x;
    __shared__ float sh_pooled[HH];
    __shared__ float sh_z[HH];
    __shared__ float sh_logits[AA];
    __shared__ float shred[2];

    float s = S[t];
    float v = s;
    for (int o = 32; o; o >>= 1) v += __shfl_down(v, o, 64);
    if ((t & 63) == 0) shred[t >> 6] = v;
    __syncthreads();
    const float T1 = shred[0] + shred[1];
    const float T2 = *T2ptr;
    const float cnt = (float)NN * (float)HH;
    const float mean = T1 / cnt;
    const float var  = T2 / cnt - mean * mean;
    const float denom = sqrtf(var) + LN_EPS;
    sh_pooled[t] = ln_w[t] * (s - (float)NN * mean) / denom + (float)NN * ln_b[t];
    __syncthreads();

    float acc = fc1_b[t];
    for (int k = 0; k < HH; ++k)
        acc = fmaf(sh_pooled[k], fc1_w[k * HH + t], acc);
    for (int k = 0; k < RR; ++k)
        acc = fmaf(esn[k], fc1_w[(HH + k) * HH + t], acc);
    sh_z[t] = fmaxf(acc, 0.f);
    __syncthreads();

    if (t < AA) {
        float l = fc2_b[t];
        for (int j = 0; j < HH; ++j)
            l = fmaf(sh_z[j], fc2_w[j * AA + t], l);
        sh_logits[t] = l;
    }
    __syncthreads();

    if (t == 0) {
        float m = sh_logits[0];
        for (int a = 1; a < AA; ++a) m = fmaxf(m, sh_logits[a]);
        float sum = 0.f;
        for (int a = 0; a < AA; ++a) sum += expf(sh_logits[a] - m);
        float lse = m + logf(sum);
        for (int a = 0; a < AA; ++a) out[a] = sh_logits[a] - lse;
    }
}

extern "C" void kernel_launch(void* const* d_in, const int* in_sizes, int n_in,
                              void* d_out, int out_size, void* d_ws, size_t ws_size,
                              hipStream_t stream) {
    const float* nf     = (const float*)d_in[0];
    const int*   ei     = (const int*)d_in[1];
    const float* esn    = (const float*)d_in[2];
    const float* gcn_w  = (const float*)d_in[3];
    const float* gcn_b  = (const float*)d_in[4];
    const float* ln_w   = (const float*)d_in[5];
    const float* ln_b   = (const float*)d_in[6];
    const float* fc1_w  = (const float*)d_in[7];
    const float* fc1_b  = (const float*)d_in[8];
    const float* fc2_w  = (const float*)d_in[9];
    const float* fc2_b  = (const float*)d_in[10];
    float* out = (float*)d_out;
    float* ws  = (float*)d_ws;

    // Bucket-path layout (word offsets):
    //   gctr:0(256) | S:256(128) | T2:384 | payload:512(NB*MAXPB) | rsv(NN) | g(2NN)
    const size_t PAYLOAD_W   = (size_t)NB * MAXPB;     // 1,806,336
    const size_t OFF_PAYLOAD = 512;
    const size_t OFF_RSV     = OFF_PAYLOAD + PAYLOAD_W;
    const size_t OFF_G       = OFF_RSV + NN;           // even -> float2 ok
    const size_t NEED_BKT    = (OFF_G + 2 * (size_t)NN) * 4;

    if (ws_size >= NEED_BKT) {
        unsigned int* gctr    = (unsigned int*)ws;
        float*        S       = ws + 256;
        float*        T2      = ws + 384;
        unsigned int* payload = (unsigned int*)ws + OFF_PAYLOAD;
        float*        rsv     = ws + OFF_RSV;
        float*        g       = ws + OFF_G;

        hipMemsetAsync(ws, 0, 512 * 4, stream);   // gctr + S + T2
        hipLaunchKernelGGL(k_scatter,   dim3(NWG_SC), dim3(SCT),  0, stream, ei, ei + EE, gctr, payload);
        hipLaunchKernelGGL(k_bdeg_g,    dim3(NB),     dim3(1024), 0, stream, gctr, payload, nf, rsv, g);
        hipLaunchKernelGGL(k_bagg_node, dim3(NB),     dim3(1024), 0, stream, gctr, payload, g, rsv, gcn_w, gcn_b, S, T2);
        hipLaunchKernelGGL(k_final,     dim3(1),      dim3(128),  0, stream,
                           S, T2, esn, ln_w, ln_b, fc1_w, fc1_b, fc2_w, fc2_b, out);
    } else {
        // Fallback: known-good atomic path.
        int*   deg  = (int*)ws;
        float* B    = ws + NN;
        float* S    = ws + 3 * (size_t)NN;
        float* T2   = ws + 3 * (size_t)NN + 128;
        float* degf = ws + 3 * (size_t)NN + 130;
        float* g    = ws + 4 * (size_t)NN + 130;
        const int eb = (EE + 255) / 256;
        const int nb = (NN + 255) / 256;
        hipLaunchKernelGGL(k_init,  dim3(2048), dim3(256), 0, stream, (unsigned int*)ws, 3 * NN + 129);
        hipLaunchKernelGGL(k_deg1,  dim3(eb),   dim3(256), 0, stream, ei + EE, deg, EE);
        hipLaunchKernelGGL(k_g1,    dim3(nb),   dim3(256), 0, stream, deg, nf, degf, g, NN);
        hipLaunchKernelGGL(k_edge1, dim3(eb),   dim3(256), 0, stream, ei, ei + EE, g, B, EE);
        hipLaunchKernelGGL(k_node,  dim3(512),  dim3(256), 0, stream, nf, degf, B, gcn_w, gcn_b, S, T2, NN);
        hipLaunchKernelGGL(k_final, dim3(1),    dim3(128), 0, stream,
                           S, T2, esn, ln_w, ln_b, fc1_w, fc1_b, fc2_w, fc2_b, out);
    }
}